// Round 1
// baseline (396.985 us; speedup 1.0000x reference)
//
#include <hip/hip_runtime.h>

#define NN 40000
#define NE 640000
#define DF 128
#define NG 2000
#define NB1 157   // ceil(NN/256)

// ---------------- degree count ----------------
__global__ void k_count(const int* __restrict__ dst, int* __restrict__ deg) {
    int e = blockIdx.x * 256 + threadIdx.x;
    if (e < NE) atomicAdd(&deg[dst[e]], 1);
}

// ---------------- scan (3 kernels) ----------------
__global__ void k_scan1(const int* __restrict__ deg, int* __restrict__ row_ptr, int* __restrict__ part) {
    __shared__ int s[256];
    int tid = threadIdx.x;
    int i = blockIdx.x * 256 + tid;
    int v = (i < NN) ? deg[i] : 0;
    s[tid] = v;
    __syncthreads();
    for (int off = 1; off < 256; off <<= 1) {
        int t = (tid >= off) ? s[tid - off] : 0;
        __syncthreads();
        s[tid] += t;
        __syncthreads();
    }
    if (i < NN) row_ptr[i] = s[tid] - v;   // block-local exclusive
    if (tid == 255) part[blockIdx.x] = s[255];
}

__global__ void k_scan2(int* __restrict__ part) {
    __shared__ int s[256];
    int tid = threadIdx.x;
    int v = (tid < NB1) ? part[tid] : 0;
    s[tid] = v;
    __syncthreads();
    for (int off = 1; off < 256; off <<= 1) {
        int t = (tid >= off) ? s[tid - off] : 0;
        __syncthreads();
        s[tid] += t;
        __syncthreads();
    }
    if (tid < NB1) part[tid] = s[tid] - v;  // exclusive
}

__global__ void k_scan3(const int* __restrict__ deg, int* __restrict__ row_ptr, const int* __restrict__ part,
                        int* __restrict__ cursor, float* __restrict__ dis) {
    int i = blockIdx.x * 256 + threadIdx.x;
    if (i < NN) {
        int r = row_ptr[i] + part[blockIdx.x];
        row_ptr[i] = r;
        cursor[i] = r;
        dis[i] = rsqrtf((float)(deg[i] + 1));  // +1 self loop; deg>=1 always
    }
    if (i == 0) row_ptr[NN] = NE;
}

// ---------------- CSR fill ----------------
__global__ void k_fill(const int* __restrict__ src, const int* __restrict__ dst,
                       int* __restrict__ cursor, int* __restrict__ col) {
    int e = blockIdx.x * 256 + threadIdx.x;
    if (e < NE) {
        int p = atomicAdd(&cursor[dst[e]], 1);
        col[p] = src[e];
    }
}

// ---------------- GEMM: out[N x 128] = act(X)[N x 128] @ W[128 x 128] ----------------
// block = 512 threads (8 waves); tile 64 rows; wave w computes cols [16w,16w+16) for all 64 rows.
// x-tile in LDS (pad 129 -> 2-way bank conflict = free); W read at wave-uniform addresses (scalar loads).
template<bool FUSE_BN>
__global__ __launch_bounds__(512) void k_gemm(const float* __restrict__ X, const float* __restrict__ W,
                                              float* __restrict__ out,
                                              const float* __restrict__ stats,
                                              const float* __restrict__ gam,
                                              const float* __restrict__ bet) {
    __shared__ float xs[64][129];
    __shared__ float sc[128], sh[128];
    int tid = threadIdx.x;
    int row0 = blockIdx.x * 64;

    if (FUSE_BN) {
        if (tid < 128) {
            const float inv_n = 1.0f / (float)NN;
            float mu = stats[tid] * inv_n;
            float va = fmaf(-mu, mu, stats[128 + tid] * inv_n);
            float rs = rsqrtf(va + 1e-5f);
            float a = gam[tid] * rs;
            sc[tid] = a;
            sh[tid] = fmaf(-mu, a, bet[tid]);
        }
        __syncthreads();
    }

    const float4* X4 = (const float4*)(X + (size_t)row0 * DF);
#pragma unroll
    for (int it = 0; it < 4; it++) {
        int idx = tid + it * 512;        // 0..2047 : 64 rows x 32 float4
        int r = idx >> 5, c4 = idx & 31;
        float4 v = X4[idx];
        if (FUSE_BN) {
            int c = c4 * 4;
            v.x = fmaxf(fmaf(v.x, sc[c + 0], sh[c + 0]), 0.f);
            v.y = fmaxf(fmaf(v.y, sc[c + 1], sh[c + 1]), 0.f);
            v.z = fmaxf(fmaf(v.z, sc[c + 2], sh[c + 2]), 0.f);
            v.w = fmaxf(fmaf(v.w, sc[c + 3], sh[c + 3]), 0.f);
        }
        float* p = &xs[r][c4 * 4];
        p[0] = v.x; p[1] = v.y; p[2] = v.z; p[3] = v.w;
    }
    __syncthreads();

    int lane = tid & 63;
    int wid = __builtin_amdgcn_readfirstlane(tid >> 6);  // wave-uniform -> SGPR
    int cb = wid * 16;
    float acc[16];
#pragma unroll
    for (int j = 0; j < 16; j++) acc[j] = 0.f;

#pragma unroll 2
    for (int k = 0; k < DF; k++) {
        float a = xs[lane][k];
        const float* wr = W + k * DF + cb;   // wave-uniform address -> s_load
#pragma unroll
        for (int j = 0; j < 16; j++) acc[j] = fmaf(a, wr[j], acc[j]);
    }

    float* o = out + (size_t)(row0 + lane) * DF + cb;
#pragma unroll
    for (int j = 0; j < 16; j += 4) {
        float4 v = make_float4(acc[j], acc[j + 1], acc[j + 2], acc[j + 3]);
        *(float4*)(o + j) = v;
    }
}

// ---------------- GCN aggregation: one wave per node ----------------
// out[i] = b + dis[i]^2 * H[i] + sum_e dis[i]*dis[src_e] * H[src_e]
__global__ __launch_bounds__(64) void k_gather(const float* __restrict__ H, const int* __restrict__ row_ptr,
                                               const int* __restrict__ col, const float* __restrict__ dis,
                                               const float* __restrict__ bias, float* __restrict__ out) {
    __shared__ int sidx[64];
    __shared__ float swgt[64];
    int i = blockIdx.x;
    int t = threadIdx.x;   // 0..63, handles 2 floats
    float di = dis[i];
    float2 a = ((const float2*)(H + (size_t)i * DF))[t];
    float self = di * di;
    float2 acc = make_float2(a.x * self, a.y * self);
    int lo = row_ptr[i], hi = row_ptr[i + 1];
    for (int base = lo; base < hi; base += 64) {
        int m = hi - base; if (m > 64) m = 64;
        if (t < m) {
            int s = col[base + t];
            sidx[t] = s;
            swgt[t] = di * dis[s];
        }
        __syncthreads();
        for (int j = 0; j < m; j++) {
            int s = sidx[j];
            float w = swgt[j];
            float2 hv = ((const float2*)(H + (size_t)s * DF))[t];
            acc.x = fmaf(hv.x, w, acc.x);
            acc.y = fmaf(hv.y, w, acc.y);
        }
        __syncthreads();
    }
    float2 b = ((const float2*)bias)[t];
    acc.x += b.x; acc.y += b.y;
    ((float2*)(out + (size_t)i * DF))[t] = acc;
}

// ---------------- BN stats: per-column sum & sumsq ----------------
__global__ void k_stats(const float* __restrict__ H, float* __restrict__ sums) {
    __shared__ float ls[256], lq[256];
    int tid = threadIdx.x;
    float s = 0.f, q = 0.f;
    for (size_t idx = (size_t)blockIdx.x * 256 + tid; idx < (size_t)NN * DF; idx += 256 * 256) {
        float v = H[idx];
        s += v;
        q = fmaf(v, v, q);
    }
    ls[tid] = s; lq[tid] = q;
    __syncthreads();
    if (tid < 128) {
        s = ls[tid] + ls[tid + 128];
        q = lq[tid] + lq[tid + 128];
        atomicAdd(&sums[tid], s);
        atomicAdd(&sums[128 + tid], q);
    }
}

// ---------------- pooling (BN2+ReLU fused), one block per graph ----------------
__global__ __launch_bounds__(128) void k_pool(const float* __restrict__ H, const int* __restrict__ batch,
                                              const float* __restrict__ sums, const float* __restrict__ gam,
                                              const float* __restrict__ bet, float* __restrict__ g0) {
    int g = blockIdx.x;
    int t = threadIdx.x;  // column
    const float inv_n = 1.0f / (float)NN;
    float mu = sums[t] * inv_n;
    float va = fmaf(-mu, mu, sums[128 + t] * inv_n);
    float rs = rsqrtf(va + 1e-5f);
    float sc = gam[t] * rs;
    float sh = fmaf(-mu, sc, bet[t]);
    // lower_bound(batch, g) and lower_bound(batch, g+1) on sorted batch
    int lo, hi;
    { int a = 0, b = NN; while (a < b) { int m = (a + b) >> 1; if (batch[m] < g) a = m + 1; else b = m; } lo = a; }
    { int a = lo, b = NN; while (a < b) { int m = (a + b) >> 1; if (batch[m] < g + 1) a = m + 1; else b = m; } hi = a; }
    float acc = 0.f;
    for (int i = lo; i < hi; i++) {
        float v = fmaf(H[(size_t)i * DF + t], sc, sh);
        acc += fmaxf(v, 0.f);
    }
    g0[(size_t)g * DF + t] = acc;
}

// ---------------- FC layers (out width 256), 4 graphs per block ----------------
template<int K, bool RELU>
__global__ __launch_bounds__(256) void k_fc(const float* __restrict__ in, const float* __restrict__ Wm,
                                            const float* __restrict__ bias, float* __restrict__ out) {
    __shared__ float rows[4 * K];
    int t = threadIdx.x;
    int gbase = blockIdx.x * 4;
    for (int i = t; i < 4 * K; i += 256) rows[i] = in[(size_t)gbase * K + i];
    __syncthreads();
    float a0 = 0.f, a1 = 0.f, a2 = 0.f, a3 = 0.f;
    for (int k = 0; k < K; k++) {
        float wv = Wm[k * 256 + t];
        a0 = fmaf(rows[k], wv, a0);
        a1 = fmaf(rows[K + k], wv, a1);
        a2 = fmaf(rows[2 * K + k], wv, a2);
        a3 = fmaf(rows[3 * K + k], wv, a3);
    }
    float bb = bias[t];
    a0 += bb; a1 += bb; a2 += bb; a3 += bb;
    if (RELU) {
        a0 = fmaxf(a0, 0.f); a1 = fmaxf(a1, 0.f); a2 = fmaxf(a2, 0.f); a3 = fmaxf(a3, 0.f);
    }
    out[(size_t)(gbase + 0) * 256 + t] = a0;
    out[(size_t)(gbase + 1) * 256 + t] = a1;
    out[(size_t)(gbase + 2) * 256 + t] = a2;
    out[(size_t)(gbase + 3) * 256 + t] = a3;
}

// ---------------- final FC -> [G,1]; one wave per graph ----------------
__global__ __launch_bounds__(256) void k_fc3(const float* __restrict__ in, const float* __restrict__ w3,
                                             const float* __restrict__ b3, float* __restrict__ out) {
    int t = threadIdx.x;
    int lane = t & 63, wv = t >> 6;
    int g = blockIdx.x * 4 + wv;
    const float* row = in + (size_t)g * 256;
    float s = fmaf(row[lane], w3[lane],
              fmaf(row[64 + lane], w3[64 + lane],
              fmaf(row[128 + lane], w3[128 + lane],
                   row[192 + lane] * w3[192 + lane])));
    for (int off = 32; off > 0; off >>= 1) s += __shfl_down(s, off);
    if (lane == 0) out[g] = s + b3[0];
}

extern "C" void kernel_launch(void* const* d_in, const int* in_sizes, int n_in,
                              void* d_out, int out_size, void* d_ws, size_t ws_size,
                              hipStream_t stream) {
    const float* x    = (const float*)d_in[0];
    const int*   ei   = (const int*)d_in[1];
    const int*   batch= (const int*)d_in[2];
    const float* W1   = (const float*)d_in[4];
    const float* b1   = (const float*)d_in[5];
    const float* W2   = (const float*)d_in[6];
    const float* b2   = (const float*)d_in[7];
    const float* bn1g = (const float*)d_in[8];
    const float* bn1b = (const float*)d_in[9];
    const float* bn2g = (const float*)d_in[10];
    const float* bn2b = (const float*)d_in[11];
    const float* fc1w = (const float*)d_in[12];
    const float* fc1b = (const float*)d_in[13];
    const float* fc2w = (const float*)d_in[14];
    const float* fc2b = (const float*)d_in[15];
    const float* fc3w = (const float*)d_in[16];
    const float* fc3b = (const float*)d_in[17];
    const int* src = ei;
    const int* dst = ei + NE;
    float* outp = (float*)d_out;

    char* w = (char*)d_ws;
    size_t o = 0;
    auto alloc = [&](size_t bytes) -> char* {
        char* p = w + o;
        o = (o + bytes + 255) & ~(size_t)255;
        return p;
    };
    int*   deg     = (int*)alloc((size_t)NN * 4);
    float* stats   = (float*)alloc(512 * 4);            // [s1(128) q1(128) s2(128) q2(128)]
    int*   row_ptr = (int*)alloc((size_t)(NN + 1) * 4);
    int*   cursor  = (int*)alloc((size_t)NN * 4);
    int*   part    = (int*)alloc((size_t)NB1 * 4);
    int*   col     = (int*)alloc((size_t)NE * 4);
    float* dis     = (float*)alloc((size_t)NN * 4);
    float* bufA    = (float*)alloc((size_t)NN * DF * 4);
    float* bufB    = (float*)alloc((size_t)NN * DF * 4);
    float* g0      = (float*)alloc((size_t)NG * 128 * 4);
    float* g1      = (float*)alloc((size_t)NG * 256 * 4);
    float* g2      = (float*)alloc((size_t)NG * 256 * 4);

    // zero deg + stats (contiguous: deg then stats)
    hipMemsetAsync(deg, 0, (size_t)(((char*)stats + 512 * 4) - (char*)deg), stream);

    // CSR build
    k_count<<<(NE + 255) / 256, 256, 0, stream>>>(dst, deg);
    k_scan1<<<NB1, 256, 0, stream>>>(deg, row_ptr, part);
    k_scan2<<<1, 256, 0, stream>>>(part);
    k_scan3<<<NB1, 256, 0, stream>>>(deg, row_ptr, part, cursor, dis);
    k_fill<<<(NE + 255) / 256, 256, 0, stream>>>(src, dst, cursor, col);

    // layer 1
    k_gemm<false><<<NN / 64, 512, 0, stream>>>(x, W1, bufA, nullptr, nullptr, nullptr);
    k_gather<<<NN, 64, 0, stream>>>(bufA, row_ptr, col, dis, b1, bufB);
    k_stats<<<256, 256, 0, stream>>>(bufB, stats);          // BN1 sums

    // layer 2 (BN1+ReLU fused into GEMM staging)
    k_gemm<true><<<NN / 64, 512, 0, stream>>>(bufB, W2, bufA, stats, bn1g, bn1b);
    k_gather<<<NN, 64, 0, stream>>>(bufA, row_ptr, col, dis, b2, bufB);
    k_stats<<<256, 256, 0, stream>>>(bufB, stats + 256);    // BN2 sums

    // pooling (BN2+ReLU fused) + MLP head
    k_pool<<<NG, 128, 0, stream>>>(bufB, batch, stats + 256, bn2g, bn2b, g0);
    k_fc<128, true><<<NG / 4, 256, 0, stream>>>(g0, fc1w, fc1b, g1);
    k_fc<256, true><<<NG / 4, 256, 0, stream>>>(g1, fc2w, fc2b, g2);
    k_fc3<<<NG / 4, 256, 0, stream>>>(g2, fc3w, fc3b, outp);
}

// Round 2
// 367.271 us; speedup vs baseline: 1.0809x; 1.0809x over previous
//
#include <hip/hip_runtime.h>

#define NN 40000
#define NE 640000
#define DF 128
#define NG 2000
#define NB1 157   // ceil(NN/256)

typedef unsigned int u32;

// ---- bf16 pair helpers (packed: low 16 bits = even col, high = odd col) ----
__device__ inline float2 bf2_to_f2(u32 u) {
    return make_float2(__uint_as_float(u << 16), __uint_as_float(u & 0xffff0000u));
}
__device__ inline u32 f_to_bf(float f) {
    u32 u = __float_as_uint(f);
    return (u + 0x7fffu + ((u >> 16) & 1u)) >> 16;   // RNE
}
__device__ inline u32 pack_bf2(float a, float b) {
    return f_to_bf(a) | (f_to_bf(b) << 16);
}

// ---------------- degree count ----------------
__global__ void k_count(const int* __restrict__ dst, int* __restrict__ deg) {
    int e = blockIdx.x * 256 + threadIdx.x;
    if (e < NE) atomicAdd(&deg[dst[e]], 1);
}

// ---------------- scan (3 kernels) ----------------
__global__ void k_scan1(const int* __restrict__ deg, int* __restrict__ row_ptr, int* __restrict__ part) {
    __shared__ int s[256];
    int tid = threadIdx.x;
    int i = blockIdx.x * 256 + tid;
    int v = (i < NN) ? deg[i] : 0;
    s[tid] = v;
    __syncthreads();
    for (int off = 1; off < 256; off <<= 1) {
        int t = (tid >= off) ? s[tid - off] : 0;
        __syncthreads();
        s[tid] += t;
        __syncthreads();
    }
    if (i < NN) row_ptr[i] = s[tid] - v;
    if (tid == 255) part[blockIdx.x] = s[255];
}

__global__ void k_scan2(int* __restrict__ part) {
    __shared__ int s[256];
    int tid = threadIdx.x;
    int v = (tid < NB1) ? part[tid] : 0;
    s[tid] = v;
    __syncthreads();
    for (int off = 1; off < 256; off <<= 1) {
        int t = (tid >= off) ? s[tid - off] : 0;
        __syncthreads();
        s[tid] += t;
        __syncthreads();
    }
    if (tid < NB1) part[tid] = s[tid] - v;
}

__global__ void k_scan3(const int* __restrict__ deg, int* __restrict__ row_ptr, const int* __restrict__ part,
                        int* __restrict__ cursor, float* __restrict__ dis) {
    int i = blockIdx.x * 256 + threadIdx.x;
    if (i < NN) {
        int r = row_ptr[i] + part[blockIdx.x];
        row_ptr[i] = r;
        cursor[i] = r;
        dis[i] = rsqrtf((float)(deg[i] + 1));
    }
    if (i == 0) row_ptr[NN] = NE;
}

// ---------------- CSR fill ----------------
__global__ void k_fill(const int* __restrict__ src, const int* __restrict__ dst,
                       int* __restrict__ cursor, int* __restrict__ col) {
    int e = blockIdx.x * 256 + threadIdx.x;
    if (e < NE) {
        int p = atomicAdd(&cursor[dst[e]], 1);
        col[p] = src[e];
    }
}

// ---------------- GEMM: outb[N x 128 bf16] = act(X)[N x 128] @ W[128 x 128] ----------------
// block = 512 threads (8 waves); tile 64 rows; wave w computes cols [16w,16w+16).
template<bool FUSE_BN, bool BF16IN>
__global__ __launch_bounds__(512) void k_gemm(const void* __restrict__ Xv, const float* __restrict__ W,
                                              u32* __restrict__ outb,
                                              const float* __restrict__ stats,
                                              const float* __restrict__ gam,
                                              const float* __restrict__ bet) {
    __shared__ float xs[64][129];
    __shared__ float sc[128], sh[128];
    int tid = threadIdx.x;
    int row0 = blockIdx.x * 64;

    if (FUSE_BN) {
        if (tid < 128) {
            const float inv_n = 1.0f / (float)NN;
            float mu = stats[tid] * inv_n;
            float va = fmaf(-mu, mu, stats[128 + tid] * inv_n);
            float rs = rsqrtf(va + 1e-5f);
            float a = gam[tid] * rs;
            sc[tid] = a;
            sh[tid] = fmaf(-mu, a, bet[tid]);
        }
        __syncthreads();
    }

    if (BF16IN) {
        const uint2* X2 = (const uint2*)((const u32*)Xv + (size_t)row0 * 64);
#pragma unroll
        for (int it = 0; it < 4; it++) {
            int idx = tid + it * 512;          // 64 rows x 32 uint2 (4 bf16 each)
            int r = idx >> 5, c = idx & 31;
            uint2 u = X2[idx];
            float2 v01 = bf2_to_f2(u.x), v23 = bf2_to_f2(u.y);
            float vv[4] = {v01.x, v01.y, v23.x, v23.y};
            int cc = c * 4;
            float* p = &xs[r][cc];
            if (FUSE_BN) {
#pragma unroll
                for (int q = 0; q < 4; q++) p[q] = fmaxf(fmaf(vv[q], sc[cc + q], sh[cc + q]), 0.f);
            } else {
#pragma unroll
                for (int q = 0; q < 4; q++) p[q] = vv[q];
            }
        }
    } else {
        const float4* X4 = (const float4*)((const float*)Xv + (size_t)row0 * DF);
#pragma unroll
        for (int it = 0; it < 4; it++) {
            int idx = tid + it * 512;          // 64 rows x 32 float4
            int r = idx >> 5, c4 = idx & 31;
            float4 v = X4[idx];
            float* p = &xs[r][c4 * 4];
            p[0] = v.x; p[1] = v.y; p[2] = v.z; p[3] = v.w;
        }
    }
    __syncthreads();

    int lane = tid & 63;
    int wid = __builtin_amdgcn_readfirstlane(tid >> 6);
    int cb = wid * 16;
    float acc[16];
#pragma unroll
    for (int j = 0; j < 16; j++) acc[j] = 0.f;

#pragma unroll 2
    for (int k = 0; k < DF; k++) {
        float a = xs[lane][k];
        const float* wr = W + k * DF + cb;     // wave-uniform -> s_load
#pragma unroll
        for (int j = 0; j < 16; j++) acc[j] = fmaf(a, wr[j], acc[j]);
    }

    u32* ob = outb + (size_t)(row0 + lane) * 64 + wid * 8;
    u32 o8[8];
#pragma unroll
    for (int j = 0; j < 8; j++) o8[j] = pack_bf2(acc[2 * j], acc[2 * j + 1]);
    ((uint4*)ob)[0] = make_uint4(o8[0], o8[1], o8[2], o8[3]);
    ((uint4*)ob)[1] = make_uint4(o8[4], o8[5], o8[6], o8[7]);
}

// ---------------- GCN aggregation: one wave per node, 4 nodes/block ----------------
// out[i] = b + dis[i]^2 * H[i] + sum_e dis[i]*dis[src_e] * H[src_e]   (bf16 in/out, fp32 accum)
__global__ __launch_bounds__(256) void k_gather(const u32* __restrict__ Hb, const int* __restrict__ row_ptr,
                                                const int* __restrict__ col, const float* __restrict__ dis,
                                                const float* __restrict__ bias, u32* __restrict__ outb) {
    int t = threadIdx.x & 63;                       // lane: handles cols 2t, 2t+1
    int node = blockIdx.x * 4 + (threadIdx.x >> 6); // NN divisible by 4
    float di = dis[node];
    float2 acc;
    {
        float2 a = bf2_to_f2(Hb[(size_t)node * 64 + t]);
        float s = di * di;
        acc = make_float2(a.x * s, a.y * s);
    }
    int lo = row_ptr[node], hi = row_ptr[node + 1];
    for (int base = lo; base < hi; base += 64) {
        int m = hi - base; if (m > 64) m = 64;
        int sidx = 0; float sw = 0.f;
        if (t < m) { sidx = col[base + t]; sw = di * dis[sidx]; }
        int j = 0;
        for (; j + 4 <= m; j += 4) {
            int s0 = __shfl(sidx, j),     s1 = __shfl(sidx, j + 1);
            int s2 = __shfl(sidx, j + 2), s3 = __shfl(sidx, j + 3);
            float w0 = __shfl(sw, j),     w1 = __shfl(sw, j + 1);
            float w2 = __shfl(sw, j + 2), w3 = __shfl(sw, j + 3);
            float2 h0 = bf2_to_f2(Hb[(size_t)s0 * 64 + t]);
            float2 h1 = bf2_to_f2(Hb[(size_t)s1 * 64 + t]);
            float2 h2 = bf2_to_f2(Hb[(size_t)s2 * 64 + t]);
            float2 h3 = bf2_to_f2(Hb[(size_t)s3 * 64 + t]);
            acc.x = fmaf(h3.x, w3, fmaf(h2.x, w2, fmaf(h1.x, w1, fmaf(h0.x, w0, acc.x))));
            acc.y = fmaf(h3.y, w3, fmaf(h2.y, w2, fmaf(h1.y, w1, fmaf(h0.y, w0, acc.y))));
        }
        for (; j < m; j++) {
            int s0 = __shfl(sidx, j); float w0 = __shfl(sw, j);
            float2 h0 = bf2_to_f2(Hb[(size_t)s0 * 64 + t]);
            acc.x = fmaf(h0.x, w0, acc.x);
            acc.y = fmaf(h0.y, w0, acc.y);
        }
    }
    float2 b = ((const float2*)bias)[t];
    acc.x += b.x; acc.y += b.y;
    outb[(size_t)node * 64 + t] = pack_bf2(acc.x, acc.y);
}

// ---------------- BN stats: per-column sum & sumsq (bf16 input) ----------------
__global__ void k_stats(const u32* __restrict__ Hb, float* __restrict__ sums) {
    __shared__ float red[4][256];
    int tid = threadIdx.x;
    float s0 = 0.f, q0 = 0.f, s1 = 0.f, q1 = 0.f;
    for (size_t idx = (size_t)blockIdx.x * 256 + tid; idx < (size_t)NN * 64; idx += 256 * 256) {
        float2 v = bf2_to_f2(Hb[idx]);   // pair index (idx & 63) == (tid & 63), invariant
        s0 += v.x; q0 = fmaf(v.x, v.x, q0);
        s1 += v.y; q1 = fmaf(v.y, v.y, q1);
    }
    red[0][tid] = s0; red[1][tid] = q0; red[2][tid] = s1; red[3][tid] = q1;
    __syncthreads();
    if (tid < 64) {
        float S0 = red[0][tid] + red[0][tid + 64] + red[0][tid + 128] + red[0][tid + 192];
        float Q0 = red[1][tid] + red[1][tid + 64] + red[1][tid + 128] + red[1][tid + 192];
        float S1 = red[2][tid] + red[2][tid + 64] + red[2][tid + 128] + red[2][tid + 192];
        float Q1 = red[3][tid] + red[3][tid + 64] + red[3][tid + 128] + red[3][tid + 192];
        atomicAdd(&sums[2 * tid], S0);
        atomicAdd(&sums[128 + 2 * tid], Q0);
        atomicAdd(&sums[2 * tid + 1], S1);
        atomicAdd(&sums[128 + 2 * tid + 1], Q1);
    }
}

// ---------------- pooling (BN2+ReLU fused), one wave per graph ----------------
__global__ __launch_bounds__(64) void k_pool(const u32* __restrict__ Hb, const int* __restrict__ batch,
                                             const float* __restrict__ sums, const float* __restrict__ gam,
                                             const float* __restrict__ bet, float* __restrict__ g0) {
    int g = blockIdx.x;
    int p = threadIdx.x;   // pair: cols 2p, 2p+1
    const float inv_n = 1.0f / (float)NN;
    float mu0 = sums[2 * p] * inv_n;
    float va0 = fmaf(-mu0, mu0, sums[128 + 2 * p] * inv_n);
    float sc0 = gam[2 * p] * rsqrtf(va0 + 1e-5f);
    float sh0 = fmaf(-mu0, sc0, bet[2 * p]);
    float mu1 = sums[2 * p + 1] * inv_n;
    float va1 = fmaf(-mu1, mu1, sums[128 + 2 * p + 1] * inv_n);
    float sc1 = gam[2 * p + 1] * rsqrtf(va1 + 1e-5f);
    float sh1 = fmaf(-mu1, sc1, bet[2 * p + 1]);
    int lo, hi;
    { int a = 0, b = NN; while (a < b) { int m = (a + b) >> 1; if (batch[m] < g) a = m + 1; else b = m; } lo = a; }
    { int a = lo, b = NN; while (a < b) { int m = (a + b) >> 1; if (batch[m] < g + 1) a = m + 1; else b = m; } hi = a; }
    float a0 = 0.f, a1 = 0.f;
    for (int i = lo; i < hi; i++) {
        float2 v = bf2_to_f2(Hb[(size_t)i * 64 + p]);
        a0 += fmaxf(fmaf(v.x, sc0, sh0), 0.f);
        a1 += fmaxf(fmaf(v.y, sc1, sh1), 0.f);
    }
    ((float2*)g0)[(size_t)g * 64 + p] = make_float2(a0, a1);
}

// ---------------- FC layers (out width 256), 4 graphs per block ----------------
template<int K, bool RELU>
__global__ __launch_bounds__(256) void k_fc(const float* __restrict__ in, const float* __restrict__ Wm,
                                            const float* __restrict__ bias, float* __restrict__ out) {
    __shared__ float rows[4 * K];
    int t = threadIdx.x;
    int gbase = blockIdx.x * 4;
    for (int i = t; i < 4 * K; i += 256) rows[i] = in[(size_t)gbase * K + i];
    __syncthreads();
    float a0 = 0.f, a1 = 0.f, a2 = 0.f, a3 = 0.f;
    for (int k = 0; k < K; k++) {
        float wv = Wm[k * 256 + t];
        a0 = fmaf(rows[k], wv, a0);
        a1 = fmaf(rows[K + k], wv, a1);
        a2 = fmaf(rows[2 * K + k], wv, a2);
        a3 = fmaf(rows[3 * K + k], wv, a3);
    }
    float bb = bias[t];
    a0 += bb; a1 += bb; a2 += bb; a3 += bb;
    if (RELU) {
        a0 = fmaxf(a0, 0.f); a1 = fmaxf(a1, 0.f); a2 = fmaxf(a2, 0.f); a3 = fmaxf(a3, 0.f);
    }
    out[(size_t)(gbase + 0) * 256 + t] = a0;
    out[(size_t)(gbase + 1) * 256 + t] = a1;
    out[(size_t)(gbase + 2) * 256 + t] = a2;
    out[(size_t)(gbase + 3) * 256 + t] = a3;
}

// ---------------- final FC -> [G,1]; one wave per graph ----------------
__global__ __launch_bounds__(256) void k_fc3(const float* __restrict__ in, const float* __restrict__ w3,
                                             const float* __restrict__ b3, float* __restrict__ out) {
    int t = threadIdx.x;
    int lane = t & 63, wv = t >> 6;
    int g = blockIdx.x * 4 + wv;
    const float* row = in + (size_t)g * 256;
    float s = fmaf(row[lane], w3[lane],
              fmaf(row[64 + lane], w3[64 + lane],
              fmaf(row[128 + lane], w3[128 + lane],
                   row[192 + lane] * w3[192 + lane])));
    for (int off = 32; off > 0; off >>= 1) s += __shfl_down(s, off);
    if (lane == 0) out[g] = s + b3[0];
}

extern "C" void kernel_launch(void* const* d_in, const int* in_sizes, int n_in,
                              void* d_out, int out_size, void* d_ws, size_t ws_size,
                              hipStream_t stream) {
    const float* x    = (const float*)d_in[0];
    const int*   ei   = (const int*)d_in[1];
    const int*   batch= (const int*)d_in[2];
    const float* W1   = (const float*)d_in[4];
    const float* b1   = (const float*)d_in[5];
    const float* W2   = (const float*)d_in[6];
    const float* b2   = (const float*)d_in[7];
    const float* bn1g = (const float*)d_in[8];
    const float* bn1b = (const float*)d_in[9];
    const float* bn2g = (const float*)d_in[10];
    const float* bn2b = (const float*)d_in[11];
    const float* fc1w = (const float*)d_in[12];
    const float* fc1b = (const float*)d_in[13];
    const float* fc2w = (const float*)d_in[14];
    const float* fc2b = (const float*)d_in[15];
    const float* fc3w = (const float*)d_in[16];
    const float* fc3b = (const float*)d_in[17];
    const int* src = ei;
    const int* dst = ei + NE;
    float* outp = (float*)d_out;

    char* w = (char*)d_ws;
    size_t o = 0;
    auto alloc = [&](size_t bytes) -> char* {
        char* p = w + o;
        o = (o + bytes + 255) & ~(size_t)255;
        return p;
    };
    int*   deg     = (int*)alloc((size_t)NN * 4);
    float* stats   = (float*)alloc(512 * 4);            // [s1 q1 s2 q2] x128
    int*   row_ptr = (int*)alloc((size_t)(NN + 1) * 4);
    int*   cursor  = (int*)alloc((size_t)NN * 4);
    int*   part    = (int*)alloc((size_t)NB1 * 4);
    int*   col     = (int*)alloc((size_t)NE * 4);
    float* dis     = (float*)alloc((size_t)NN * 4);
    u32*   bufA    = (u32*)alloc((size_t)NN * 64 * 4);  // bf16 H
    u32*   bufB    = (u32*)alloc((size_t)NN * 64 * 4);  // bf16 agg out
    float* g0      = (float*)alloc((size_t)NG * 128 * 4);
    float* g1      = (float*)alloc((size_t)NG * 256 * 4);
    float* g2      = (float*)alloc((size_t)NG * 256 * 4);

    // zero deg + stats (contiguous)
    hipMemsetAsync(deg, 0, (size_t)(((char*)stats + 512 * 4) - (char*)deg), stream);

    // CSR build
    k_count<<<(NE + 255) / 256, 256, 0, stream>>>(dst, deg);
    k_scan1<<<NB1, 256, 0, stream>>>(deg, row_ptr, part);
    k_scan2<<<1, 256, 0, stream>>>(part);
    k_scan3<<<NB1, 256, 0, stream>>>(deg, row_ptr, part, cursor, dis);
    k_fill<<<(NE + 255) / 256, 256, 0, stream>>>(src, dst, cursor, col);

    // layer 1
    k_gemm<false, false><<<NN / 64, 512, 0, stream>>>(x, W1, bufA, nullptr, nullptr, nullptr);
    k_gather<<<NN / 4, 256, 0, stream>>>(bufA, row_ptr, col, dis, b1, bufB);
    k_stats<<<256, 256, 0, stream>>>(bufB, stats);

    // layer 2 (BN1+ReLU fused into GEMM staging)
    k_gemm<true, true><<<NN / 64, 512, 0, stream>>>(bufB, W2, bufA, stats, bn1g, bn1b);
    k_gather<<<NN / 4, 256, 0, stream>>>(bufA, row_ptr, col, dis, b2, bufB);
    k_stats<<<256, 256, 0, stream>>>(bufB, stats + 256);

    // pooling (BN2+ReLU fused) + MLP head
    k_pool<<<NG, 64, 0, stream>>>(bufB, batch, stats + 256, bn2g, bn2b, g0);
    k_fc<128, true><<<NG / 4, 256, 0, stream>>>(g0, fc1w, fc1b, g1);
    k_fc<256, true><<<NG / 4, 256, 0, stream>>>(g1, fc2w, fc2b, g2);
    k_fc3<<<NG / 4, 256, 0, stream>>>(g2, fc3w, fc3b, outp);
}